// Round 1
// baseline (477.367 us; speedup 1.0000x reference)
//
#include <hip/hip_runtime.h>
#include <math.h>

// ModifiedBarlowTwinsLoss — algebraic reduction.
// loss = (1/D^2) sum_{k,l} Ga~[k,l] Gb~[k,l]  - (2/D) sum_c Sa~[c]·Sb~[c] + sum_c n_c^2
// where Ga~ = normalized Gram (D x D), Sa~ = normalized per-class row sums.
// Normalization folded in after raw Gram / raw class sums (ddof=1 std).

#define NN 8192
#define DD 512
#define NC 100

// ws layout (float index offsets)
#define GA_OFF   0                    // 512*512
#define GB_OFF   262144               // 512*512
#define RA_OFF   524288               // 100*512
#define RB_OFF   575488               // 100*512
#define MUA_OFF  626688               // 512
#define MUB_OFF  627200               // 512
#define RSA_OFF  627712               // 512
#define RSB_OFF  628224               // 512
#define CNT_OFF  628736               // 100 ints
#define OFFS_OFF 628836               // 100 ints
#define ROWL_OFF 628936               // 8192 ints
// total ~637128 floats ~2.55 MB

__device__ __forceinline__ float block_reduce_sum(float v) {
    __shared__ float red[8];
    int lane = threadIdx.x & 63;
    int wave = threadIdx.x >> 6;
    #pragma unroll
    for (int off = 32; off > 0; off >>= 1) v += __shfl_down(v, off, 64);
    if (lane == 0) red[wave] = v;
    __syncthreads();
    float s = 0.f;
    if (threadIdx.x == 0) {
        int nw = (blockDim.x + 63) >> 6;
        for (int w = 0; w < nw; w++) s += red[w];
    }
    return s; // valid in thread 0 only
}

// K0: zero atomic accumulators (Ga, Gb) and the output scalar.
__global__ void k_zero(float* ws, float* out) {
    int i = blockIdx.x * blockDim.x + threadIdx.x;
    int stride = gridDim.x * blockDim.x;
    for (int j = i; j < 2 * DD * DD; j += stride) ws[j] = 0.f;
    if (i == 0) out[0] = 0.f;
}

// K1: histogram labels, prefix-sum offsets, scatter row indices per class.
__global__ void k_buckets(const int* labels, int* counts, int* offsets, int* rowlist) {
    __shared__ int lcnt[NC], loff[NC], lcur[NC];
    int t = threadIdx.x;
    for (int c = t; c < NC; c += blockDim.x) { lcnt[c] = 0; lcur[c] = 0; }
    __syncthreads();
    for (int i = t; i < NN; i += blockDim.x) atomicAdd(&lcnt[labels[i]], 1);
    __syncthreads();
    if (t == 0) {
        int acc = 0;
        for (int c = 0; c < NC; c++) { loff[c] = acc; acc += lcnt[c]; }
    }
    __syncthreads();
    for (int c = t; c < NC; c += blockDim.x) { counts[c] = lcnt[c]; offsets[c] = loff[c]; }
    for (int i = t; i < NN; i += blockDim.x) {
        int lab = labels[i];
        int pos = atomicAdd(&lcur[lab], 1);
        rowlist[loff[lab] + pos] = i;
    }
}

// K2: per-class raw column sums R[c,k] = sum_{i in class c} X[i,k].
// grid: 2*NC blocks (mat-major), 512 threads (one per column).
__global__ void k_classsum(const float* __restrict__ A, const float* __restrict__ B,
                           const int* __restrict__ counts, const int* __restrict__ offsets,
                           const int* __restrict__ rowlist,
                           float* __restrict__ Ra, float* __restrict__ Rb) {
    int c = blockIdx.x % NC;
    const float* X = (blockIdx.x < NC) ? A : B;
    float* R = (blockIdx.x < NC) ? Ra : Rb;
    int t = threadIdx.x;
    int n = counts[c], off = offsets[c];
    float s = 0.f;
    for (int r = 0; r < n; r++) {
        int row = rowlist[off + r];               // wave-uniform -> scalar load
        s += X[(size_t)row * DD + t];             // coalesced 2KB per row
    }
    R[c * DD + t] = s;
}

// K4: raw Gram G = X^T X via 128x128 output tiles, split-K (8 chunks of 1024),
// 8x8 micro-tile per thread, fp32, atomicAdd merge.
// grid = 256: bid<128 -> matrix A, else B. rem: kc = rem>>4, tile = rem&15.
__global__ __launch_bounds__(256) void k_gram(const float* __restrict__ A,
                                              const float* __restrict__ B,
                                              float* __restrict__ Ga, float* __restrict__ Gb) {
    int bid = blockIdx.x;
    const float* X = (bid < 128) ? A : B;
    float* G = (bid < 128) ? Ga : Gb;
    int rem = bid & 127;
    int kc = rem >> 4;       // 0..7
    int tile = rem & 15;     // 4x4 tiles over 512x512
    int ti = tile >> 2, tj = tile & 3;
    int I = ti * 128, J = tj * 128;
    int k0 = kc * 1024;

    __shared__ float LA[8][128];
    __shared__ float LB[8][128];

    int t = threadIdx.x;
    int lr = t >> 5;             // 0..7 (stage row)
    int lc = (t & 31) << 2;      // col*4 (float4 lane)
    int ty = t >> 4, tx = t & 15;

    float acc[8][8] = {};

    for (int ks = 0; ks < 1024; ks += 8) {
        const float* src = X + (size_t)(k0 + ks + lr) * DD;
        float4 va = *(const float4*)(src + I + lc);
        float4 vb = *(const float4*)(src + J + lc);
        __syncthreads();
        *(float4*)&LA[lr][lc] = va;
        *(float4*)&LB[lr][lc] = vb;
        __syncthreads();
        #pragma unroll
        for (int kk = 0; kk < 8; kk++) {
            float a[8], b[8];
            #pragma unroll
            for (int i = 0; i < 8; i++) a[i] = LA[kk][ty * 8 + i];
            #pragma unroll
            for (int j = 0; j < 8; j++) b[j] = LB[kk][tx * 8 + j];
            #pragma unroll
            for (int i = 0; i < 8; i++)
                #pragma unroll
                for (int j = 0; j < 8; j++)
                    acc[i][j] += a[i] * b[j];
        }
    }

    #pragma unroll
    for (int i = 0; i < 8; i++) {
        int gi = I + ty * 8 + i;
        #pragma unroll
        for (int j = 0; j < 8; j++) {
            int gj = J + tx * 8 + j;
            atomicAdd(&G[gi * DD + gj], acc[i][j]);
        }
    }
}

// K3: column stats. mean from class sums; sumsq from Gram diagonal; rstd (ddof=1).
__global__ void k_stats(const float* __restrict__ Ga, const float* __restrict__ Gb,
                        const float* __restrict__ Ra, const float* __restrict__ Rb,
                        float* mu_a, float* mu_b, float* rstd_a, float* rstd_b) {
    int mat = blockIdx.x;
    int k = threadIdx.x;
    const float* G = mat ? Gb : Ga;
    const float* R = mat ? Rb : Ra;
    float* mu = mat ? mu_b : mu_a;
    float* rstd = mat ? rstd_b : rstd_a;
    float s = 0.f;
    for (int c = 0; c < NC; c++) s += R[c * DD + k];
    float m = s / (float)NN;
    float sumsq = G[k * DD + k];
    float var = (sumsq - (float)NN * m * m) / (float)(NN - 1);
    mu[k] = m;
    rstd[k] = rsqrtf(var);
}

// K5: term1 = (1/D^2) sum_{k,l} Ga~ * Gb~  (normalization applied on the fly)
__global__ void k_term1(const float* __restrict__ Ga, const float* __restrict__ Gb,
                        const float* __restrict__ mu_a, const float* __restrict__ mu_b,
                        const float* __restrict__ rstd_a, const float* __restrict__ rstd_b,
                        float* out) {
    int idx = blockIdx.x * blockDim.x + threadIdx.x;
    int stride = gridDim.x * blockDim.x;
    float local = 0.f;
    for (int x = idx; x < DD * DD; x += stride) {
        int k = x >> 9, l = x & (DD - 1);
        float ga = rstd_a[k] * rstd_a[l] * (Ga[x] - (float)NN * mu_a[k] * mu_a[l]);
        float gb = rstd_b[k] * rstd_b[l] * (Gb[x] - (float)NN * mu_b[k] * mu_b[l]);
        local += ga * gb;
    }
    float s = block_reduce_sum(local);
    if (threadIdx.x == 0) atomicAdd(out, s * (1.0f / ((float)DD * (float)DD)));
}

// K6: term2 = -(2/D) sum_c Sa~·Sb~ ; term3 = sum_c n_c^2 (added by block 0).
__global__ void k_term23(const float* __restrict__ Ra, const float* __restrict__ Rb,
                         const int* __restrict__ counts,
                         const float* __restrict__ mu_a, const float* __restrict__ mu_b,
                         const float* __restrict__ rstd_a, const float* __restrict__ rstd_b,
                         float* out) {
    int c = blockIdx.x;
    int k = threadIdx.x;
    float n = (float)counts[c];
    float ta = rstd_a[k] * (Ra[c * DD + k] - n * mu_a[k]);
    float tb = rstd_b[k] * (Rb[c * DD + k] - n * mu_b[k]);
    float s = block_reduce_sum(ta * tb);
    if (threadIdx.x == 0) {
        float add = s * (-2.0f / (float)DD);
        if (c == 0) {
            float t3 = 0.f;
            for (int cc = 0; cc < NC; cc++) {
                float nc = (float)counts[cc];
                t3 += nc * nc;
            }
            add += t3;
        }
        atomicAdd(out, add);
    }
}

extern "C" void kernel_launch(void* const* d_in, const int* in_sizes, int n_in,
                              void* d_out, int out_size, void* d_ws, size_t ws_size,
                              hipStream_t stream) {
    const float* z_a = (const float*)d_in[0];
    const float* z_b = (const float*)d_in[1];
    const int* labels = (const int*)d_in[2];
    float* out = (float*)d_out;
    float* ws = (float*)d_ws;

    float* Ga = ws + GA_OFF;
    float* Gb = ws + GB_OFF;
    float* Ra = ws + RA_OFF;
    float* Rb = ws + RB_OFF;
    float* mu_a = ws + MUA_OFF;
    float* mu_b = ws + MUB_OFF;
    float* rstd_a = ws + RSA_OFF;
    float* rstd_b = ws + RSB_OFF;
    int* counts = (int*)(ws + CNT_OFF);
    int* offsets = (int*)(ws + OFFS_OFF);
    int* rowlist = (int*)(ws + ROWL_OFF);

    hipLaunchKernelGGL(k_zero, dim3(512), dim3(256), 0, stream, ws, out);
    hipLaunchKernelGGL(k_buckets, dim3(1), dim3(256), 0, stream, labels, counts, offsets, rowlist);
    hipLaunchKernelGGL(k_classsum, dim3(2 * NC), dim3(DD), 0, stream,
                       z_a, z_b, counts, offsets, rowlist, Ra, Rb);
    hipLaunchKernelGGL(k_gram, dim3(256), dim3(256), 0, stream, z_a, z_b, Ga, Gb);
    hipLaunchKernelGGL(k_stats, dim3(2), dim3(DD), 0, stream,
                       Ga, Gb, Ra, Rb, mu_a, mu_b, rstd_a, rstd_b);
    hipLaunchKernelGGL(k_term1, dim3(256), dim3(256), 0, stream,
                       Ga, Gb, mu_a, mu_b, rstd_a, rstd_b, out);
    hipLaunchKernelGGL(k_term23, dim3(NC), dim3(DD), 0, stream,
                       Ra, Rb, counts, mu_a, mu_b, rstd_a, rstd_b, out);
}

// Round 2
// 135.798 us; speedup vs baseline: 3.5153x; 3.5153x over previous
//
#include <hip/hip_runtime.h>
#include <math.h>

// ModifiedBarlowTwinsLoss — algebraic reduction + bf16 MFMA Gram.
// loss = (1/D^2) sum_{k,l} Ga~ Gb~  - (2/D) sum_c Sa~·Sb~ + sum_c n_c^2
// Gram G = X^T X computed in bf16 MFMA (16x16x32), upper triangle only
// (G symmetric), split-K partials in ws, no atomics on the hot path.

#define NN 8192
#define DD 512
#define NC 100
#define SPLITK 16           // K chunks of 512
#define NTILES 10           // upper-triangle 128x128 tiles of 512x512

// ws byte offsets
#define GA_B    0u           // 512*512*4 = 1,048,576
#define GB_B    1048576u
#define RA_B    2097152u     // 100*512*4
#define RB_B    2301952u
#define MUA_B   2506752u     // 512*4
#define MUB_B   2508800u
#define RSA_B   2510848u
#define RSB_B   2512896u
#define CNT_B   2514944u     // 100*4
#define OFF_B   2515344u
#define ROWL_B  2515744u     // 8192*4
#define XTA_B   2621440u     // 512*8192*2 = 8,388,608
#define XTB_B   11010048u
#define PART_B  19398656u    // 2*16*10*16384*4 = 20,971,520  (end ~40.4 MB)

typedef __attribute__((ext_vector_type(8))) short short8;
typedef __attribute__((ext_vector_type(4))) float f32x4;

__device__ __forceinline__ short f2bf_rne(float f) {
    unsigned int u = __builtin_bit_cast(unsigned int, f);
    u += 0x7fffu + ((u >> 16) & 1u);
    return (short)(u >> 16);
}

__device__ __forceinline__ float block_reduce_sum(float v) {
    __shared__ float red[8];
    int lane = threadIdx.x & 63;
    int wave = threadIdx.x >> 6;
    #pragma unroll
    for (int off = 32; off > 0; off >>= 1) v += __shfl_down(v, off, 64);
    if (lane == 0) red[wave] = v;
    __syncthreads();
    float s = 0.f;
    if (threadIdx.x == 0) {
        int nw = (blockDim.x + 63) >> 6;
        for (int w = 0; w < nw; w++) s += red[w];
    }
    return s; // valid in thread 0 only
}

// K0: zero the output scalar (atomicAdd target).
__global__ void k_zero(float* out) {
    if (threadIdx.x == 0) out[0] = 0.f;
}

// K1: histogram labels, prefix-sum offsets, scatter row indices per class.
__global__ void k_buckets(const int* labels, int* counts, int* offsets, int* rowlist) {
    __shared__ int lcnt[NC], loff[NC], lcur[NC];
    int t = threadIdx.x;
    for (int c = t; c < NC; c += blockDim.x) { lcnt[c] = 0; lcur[c] = 0; }
    __syncthreads();
    for (int i = t; i < NN; i += blockDim.x) atomicAdd(&lcnt[labels[i]], 1);
    __syncthreads();
    if (t == 0) {
        int acc = 0;
        for (int c = 0; c < NC; c++) { loff[c] = acc; acc += lcnt[c]; }
    }
    __syncthreads();
    for (int c = t; c < NC; c += blockDim.x) { counts[c] = lcnt[c]; offsets[c] = loff[c]; }
    for (int i = t; i < NN; i += blockDim.x) {
        int lab = labels[i];
        int pos = atomicAdd(&lcur[lab], 1);
        rowlist[loff[lab] + pos] = i;
    }
}

// K2: per-class raw column sums R[c,k] = sum_{i in class c} X[i,k].
__global__ void k_classsum(const float* __restrict__ A, const float* __restrict__ B,
                           const int* __restrict__ counts, const int* __restrict__ offsets,
                           const int* __restrict__ rowlist,
                           float* __restrict__ Ra, float* __restrict__ Rb) {
    int c = blockIdx.x % NC;
    const float* X = (blockIdx.x < NC) ? A : B;
    float* R = (blockIdx.x < NC) ? Ra : Rb;
    int t = threadIdx.x;
    int n = counts[c], off = offsets[c];
    float s = 0.f;
    int r = 0;
    for (; r + 4 <= n; r += 4) {
        int i0 = rowlist[off + r + 0];
        int i1 = rowlist[off + r + 1];
        int i2 = rowlist[off + r + 2];
        int i3 = rowlist[off + r + 3];
        s += X[(size_t)i0 * DD + t] + X[(size_t)i1 * DD + t]
           + X[(size_t)i2 * DD + t] + X[(size_t)i3 * DD + t];
    }
    for (; r < n; r++) s += X[(size_t)rowlist[off + r] * DD + t];
    R[c * DD + t] = s;
}

// K3: fp32 -> bf16 transpose-convert. X[8192][512] f32 -> XT[512][8192] bf16.
// grid 2*8*128 blocks (mat, col-tile 64, k-tile 64), 256 threads.
__global__ __launch_bounds__(256) void k_convT(const float* __restrict__ A,
                                               const float* __restrict__ B,
                                               short* __restrict__ XTa,
                                               short* __restrict__ XTb) {
    __shared__ short LT[64][72];
    int bid = blockIdx.x;
    const float* X = (bid >> 10) ? B : A;
    short* XT = (bid >> 10) ? XTb : XTa;
    int rem = bid & 1023;
    int c0 = (rem >> 7) << 6;    // 0..448
    int k0 = (rem & 127) << 6;   // 0..8128
    int t = threadIdx.x;

    int cc = t & 15;             // col chunk (4 floats)
    int kb = t >> 4;             // 0..15
    #pragma unroll
    for (int s = 0; s < 4; s++) {
        int kr = kb + s * 16;
        float4 v = *(const float4*)&X[(size_t)(k0 + kr) * DD + c0 + cc * 4];
        LT[cc * 4 + 0][kr] = f2bf_rne(v.x);
        LT[cc * 4 + 1][kr] = f2bf_rne(v.y);
        LT[cc * 4 + 2][kr] = f2bf_rne(v.z);
        LT[cc * 4 + 3][kr] = f2bf_rne(v.w);
    }
    __syncthreads();
    #pragma unroll
    for (int s = 0; s < 2; s++) {
        int idx = s * 256 + t;
        int orow = idx >> 3;     // 0..63
        int och = idx & 7;       // 8-short chunk
        *(uint4*)&XT[(size_t)(c0 + orow) * NN + k0 + och * 8] =
            *(const uint4*)&LT[orow][och * 8];
    }
}

// K4: bf16 MFMA Gram, 128x128 upper-triangle tiles, split-K=16.
// grid = 2 * 16 * 10 = 320 blocks, 256 threads (4 waves, 2x2 of 64x64).
__constant__ int c_ti[NTILES] = {0,0,0,0,1,1,1,2,2,3};
__constant__ int c_tj[NTILES] = {0,1,2,3,1,2,3,2,3,3};

__global__ __launch_bounds__(256) void k_gram_mfma(const short* __restrict__ XTa,
                                                   const short* __restrict__ XTb,
                                                   float* __restrict__ part) {
    __shared__ short LA[128][72];
    __shared__ short LB[128][72];

    int bid = blockIdx.x;
    int mat = bid / 160;
    int rem = bid % 160;
    int chunk = rem / NTILES;
    int tile = rem % NTILES;
    const short* XT = mat ? XTb : XTa;
    int I = c_ti[tile] * 128, J = c_tj[tile] * 128;
    int k0 = chunk * (NN / SPLITK);   // 512-wide K chunk

    int t = threadIdx.x;
    int wave = t >> 6, lane = t & 63;
    int quad = lane >> 4, l16 = lane & 15;
    int wrow = (wave >> 1) * 64, wcol = (wave & 1) * 64;

    f32x4 acc[4][4];
    #pragma unroll
    for (int i = 0; i < 4; i++)
        #pragma unroll
        for (int j = 0; j < 4; j++) acc[i][j] = (f32x4)0.f;

    for (int kk = 0; kk < NN / SPLITK; kk += 64) {
        __syncthreads();
        #pragma unroll
        for (int rr = 0; rr < 4; rr++) {
            int idx = rr * 256 + t;
            int row = idx >> 3;
            int ch = idx & 7;
            size_t g = (size_t)(k0 + kk) + (size_t)ch * 8;
            uint4 va = *(const uint4*)&XT[(size_t)(I + row) * NN + g];
            uint4 vb = *(const uint4*)&XT[(size_t)(J + row) * NN + g];
            *(uint4*)&LA[row][ch * 8] = va;
            *(uint4*)&LB[row][ch * 8] = vb;
        }
        __syncthreads();
        #pragma unroll
        for (int ks = 0; ks < 2; ks++) {
            short8 a[4], b[4];
            #pragma unroll
            for (int mt = 0; mt < 4; mt++)
                a[mt] = *(const short8*)&LA[wrow + mt * 16 + l16][ks * 32 + quad * 8];
            #pragma unroll
            for (int nt = 0; nt < 4; nt++)
                b[nt] = *(const short8*)&LB[wcol + nt * 16 + l16][ks * 32 + quad * 8];
            #pragma unroll
            for (int mt = 0; mt < 4; mt++)
                #pragma unroll
                for (int nt = 0; nt < 4; nt++)
                    acc[mt][nt] = __builtin_amdgcn_mfma_f32_16x16x32_bf16(
                        a[mt], b[nt], acc[mt][nt], 0, 0, 0);
        }
    }

    float* pbase = part + ((size_t)((mat * SPLITK + chunk) * NTILES + tile)) * 16384;
    #pragma unroll
    for (int mt = 0; mt < 4; mt++) {
        #pragma unroll
        for (int nt = 0; nt < 4; nt++) {
            #pragma unroll
            for (int r = 0; r < 4; r++) {
                int rr = wrow + mt * 16 + quad * 4 + r;
                int cc = wcol + nt * 16 + l16;
                pbase[rr * 128 + cc] = acc[mt][nt][r];
            }
        }
    }
}

// K5: sum the 16 split-K partials into Ga/Gb (upper-tile region only).
// grid = 2*10*64 blocks, 256 threads, one elem per thread.
__global__ void k_gsum(const float* __restrict__ part,
                       float* __restrict__ Ga, float* __restrict__ Gb) {
    int bid = blockIdx.x;
    int mat = bid / (NTILES * 64);
    int rem = bid % (NTILES * 64);
    int tile = rem / 64;
    int bb = rem % 64;
    int e = bb * 256 + threadIdx.x;        // 0..16383
    const float* p = part + ((size_t)(mat * SPLITK) * NTILES + tile) * 16384 + e;
    float s = 0.f;
    #pragma unroll
    for (int c = 0; c < SPLITK; c++) s += p[(size_t)c * NTILES * 16384];
    int r = e >> 7, cl = e & 127;
    int gi = c_ti[tile] * 128 + r, gj = c_tj[tile] * 128 + cl;
    float* G = mat ? Gb : Ga;
    G[gi * DD + gj] = s;
}

// K6: column stats. mean from class sums; sumsq from Gram diagonal; rstd (ddof=1).
__global__ void k_stats(const float* __restrict__ Ga, const float* __restrict__ Gb,
                        const float* __restrict__ Ra, const float* __restrict__ Rb,
                        float* mu_a, float* mu_b, float* rstd_a, float* rstd_b) {
    int mat = blockIdx.x;
    int k = threadIdx.x;
    const float* G = mat ? Gb : Ga;
    const float* R = mat ? Rb : Ra;
    float* mu = mat ? mu_b : mu_a;
    float* rstd = mat ? rstd_b : rstd_a;
    float s = 0.f;
    for (int c = 0; c < NC; c++) s += R[c * DD + k];
    float m = s / (float)NN;
    float sumsq = G[k * DD + k];
    float var = (sumsq - (float)NN * m * m) / (float)(NN - 1);
    mu[k] = m;
    rstd[k] = rsqrtf(var);
}

// K7: term1 = (1/D^2) sum_{k,l} Ga~ Gb~, using symmetry: upper with weight 2.
__global__ void k_term1(const float* __restrict__ Ga, const float* __restrict__ Gb,
                        const float* __restrict__ mu_a, const float* __restrict__ mu_b,
                        const float* __restrict__ rstd_a, const float* __restrict__ rstd_b,
                        float* out) {
    int idx = blockIdx.x * blockDim.x + threadIdx.x;
    int stride = gridDim.x * blockDim.x;
    float local = 0.f;
    for (int x = idx; x < DD * DD; x += stride) {
        int k = x >> 9, l = x & (DD - 1);
        if (l < k) continue;
        float w = (l == k) ? 1.f : 2.f;
        float ga = rstd_a[k] * rstd_a[l] * (Ga[x] - (float)NN * mu_a[k] * mu_a[l]);
        float gb = rstd_b[k] * rstd_b[l] * (Gb[x] - (float)NN * mu_b[k] * mu_b[l]);
        local += w * ga * gb;
    }
    float s = block_reduce_sum(local);
    if (threadIdx.x == 0) atomicAdd(out, s * (1.0f / ((float)DD * (float)DD)));
}

// K8: term2 = -(2/D) sum_c Sa~·Sb~ ; term3 = sum_c n_c^2 (added by block 0).
__global__ void k_term23(const float* __restrict__ Ra, const float* __restrict__ Rb,
                         const int* __restrict__ counts,
                         const float* __restrict__ mu_a, const float* __restrict__ mu_b,
                         const float* __restrict__ rstd_a, const float* __restrict__ rstd_b,
                         float* out) {
    int c = blockIdx.x;
    int k = threadIdx.x;
    float n = (float)counts[c];
    float ta = rstd_a[k] * (Ra[c * DD + k] - n * mu_a[k]);
    float tb = rstd_b[k] * (Rb[c * DD + k] - n * mu_b[k]);
    float s = block_reduce_sum(ta * tb);
    if (threadIdx.x == 0) {
        float add = s * (-2.0f / (float)DD);
        if (c == 0) {
            float t3 = 0.f;
            for (int cc = 0; cc < NC; cc++) {
                float nc = (float)counts[cc];
                t3 += nc * nc;
            }
            add += t3;
        }
        atomicAdd(out, add);
    }
}

extern "C" void kernel_launch(void* const* d_in, const int* in_sizes, int n_in,
                              void* d_out, int out_size, void* d_ws, size_t ws_size,
                              hipStream_t stream) {
    const float* z_a = (const float*)d_in[0];
    const float* z_b = (const float*)d_in[1];
    const int* labels = (const int*)d_in[2];
    float* out = (float*)d_out;
    char* wsb = (char*)d_ws;

    float* Ga = (float*)(wsb + GA_B);
    float* Gb = (float*)(wsb + GB_B);
    float* Ra = (float*)(wsb + RA_B);
    float* Rb = (float*)(wsb + RB_B);
    float* mu_a = (float*)(wsb + MUA_B);
    float* mu_b = (float*)(wsb + MUB_B);
    float* rstd_a = (float*)(wsb + RSA_B);
    float* rstd_b = (float*)(wsb + RSB_B);
    int* counts = (int*)(wsb + CNT_B);
    int* offsets = (int*)(wsb + OFF_B);
    int* rowlist = (int*)(wsb + ROWL_B);
    short* XTa = (short*)(wsb + XTA_B);
    short* XTb = (short*)(wsb + XTB_B);
    float* part = (float*)(wsb + PART_B);

    hipLaunchKernelGGL(k_zero, dim3(1), dim3(64), 0, stream, out);
    hipLaunchKernelGGL(k_buckets, dim3(1), dim3(1024), 0, stream, labels, counts, offsets, rowlist);
    hipLaunchKernelGGL(k_classsum, dim3(2 * NC), dim3(DD), 0, stream,
                       z_a, z_b, counts, offsets, rowlist, Ra, Rb);
    hipLaunchKernelGGL(k_convT, dim3(2048), dim3(256), 0, stream, z_a, z_b, XTa, XTb);
    hipLaunchKernelGGL(k_gram_mfma, dim3(320), dim3(256), 0, stream, XTa, XTb, part);
    hipLaunchKernelGGL(k_gsum, dim3(2 * NTILES * 64), dim3(256), 0, stream, part, Ga, Gb);
    hipLaunchKernelGGL(k_stats, dim3(2), dim3(DD), 0, stream,
                       Ga, Gb, Ra, Rb, mu_a, mu_b, rstd_a, rstd_b);
    hipLaunchKernelGGL(k_term1, dim3(256), dim3(256), 0, stream,
                       Ga, Gb, mu_a, mu_b, rstd_a, rstd_b, out);
    hipLaunchKernelGGL(k_term23, dim3(NC), dim3(DD), 0, stream,
                       Ra, Rb, counts, mu_a, mu_b, rstd_a, rstd_b, out);
}

// Round 3
// 118.336 us; speedup vs baseline: 4.0340x; 1.1476x over previous
//
#include <hip/hip_runtime.h>
#include <math.h>

// ModifiedBarlowTwinsLoss — augmented-Gram formulation, bf16 MFMA.
// Y = [X | M] (M = one-hot labels, 128 padded classes). One MFMA pass gives:
//   X^T X  (10 upper 128x128 tiles)  -> Gram for term1 + column sumsq
//   X^T M  (4 tiles)                 -> per-class column sums R (term2, mu)
// loss = (1/D^2) sum Ga~ Gb~ - (2/D) sum_c Sa~·Sb~ + sum_c n_c^2

#define NN 8192
#define DD 512
#define NC 100
#define SPLITK 16
#define NXT 10            // X^T X upper-triangle tiles
#define NTILE 14          // + 4 X^T M tiles

// ws byte offsets
#define GA_B    0u           // 512*512*4
#define GB_B    1048576u
#define RTA_B   2097152u     // RT: [128 classes][512 cols] f32 = 262144 B
#define RTB_B   2359296u
#define MUA_B   2621440u
#define MUB_B   2623488u
#define RSA_B   2625536u
#define RSB_B   2627584u
#define CNT_B   2629632u
#define XTA_B   4194304u     // 512*8192*2
#define XTB_B   12582912u
#define MT_B    20971520u    // 128*8192*2
#define PART_B  23068672u    // 2*14*16*16384*4 = 29,360,128 (end ~52.4 MB)

typedef __attribute__((ext_vector_type(8))) short short8;
typedef __attribute__((ext_vector_type(4))) float f32x4;

__constant__ int c_ti[NTILE] = {0,0,0,0,1,1,1,2,2,3, 0,1,2,3};
__constant__ int c_tj[NTILE] = {0,1,2,3,1,2,3,2,3,3, 4,4,4,4};
__constant__ float c_w[NXT]  = {1.f,2.f,2.f,2.f,1.f,2.f,2.f,1.f,2.f,1.f};

#if defined(__has_builtin)
#if __has_builtin(__builtin_amdgcn_global_load_lds)
#define HAVE_GLL 1
#endif
#endif

#ifdef HAVE_GLL
__device__ __forceinline__ void async16(const void* g, void* l) {
    __builtin_amdgcn_global_load_lds(
        (const __attribute__((address_space(1))) void*)g,
        (__attribute__((address_space(3))) void*)l, 16, 0, 0);
}
#endif

__device__ __forceinline__ short f2bf_rne(float f) {
    unsigned int u = __builtin_bit_cast(unsigned int, f);
    u += 0x7fffu + ((u >> 16) & 1u);
    return (short)(u >> 16);
}

__device__ __forceinline__ float block_reduce_sum(float v) {
    __shared__ float red[8];
    int lane = threadIdx.x & 63;
    int wave = threadIdx.x >> 6;
    #pragma unroll
    for (int off = 32; off > 0; off >>= 1) v += __shfl_down(v, off, 64);
    if (lane == 0) red[wave] = v;
    __syncthreads();
    float s = 0.f;
    if (threadIdx.x == 0) {
        int nw = (blockDim.x + 63) >> 6;
        for (int w = 0; w < nw; w++) s += red[w];
    }
    return s; // thread 0 only
}

// K1: build one-hot MT[128][8192] bf16; block 128 zeroes the output scalar.
__global__ void k_init(const int* __restrict__ labels, short* __restrict__ MT,
                       float* __restrict__ out) {
    int c = blockIdx.x;
    if (c == 128) { if (threadIdx.x == 0) out[0] = 0.f; return; }
    int t = threadIdx.x;
    unsigned short one = 0x3F80; // bf16 1.0
    ushort4* dst = (ushort4*)(MT + (size_t)c * NN);
    const int4* lb4 = (const int4*)labels;
    #pragma unroll
    for (int j = 0; j < 8; j++) {
        int i4 = j * 256 + t;
        int4 lb = lb4[i4];
        ushort4 v;
        v.x = (lb.x == c) ? one : (unsigned short)0;
        v.y = (lb.y == c) ? one : (unsigned short)0;
        v.z = (lb.z == c) ? one : (unsigned short)0;
        v.w = (lb.w == c) ? one : (unsigned short)0;
        dst[i4] = v;
    }
}

// K2: fp32 -> bf16 transpose-convert. X[8192][512] f32 -> XT[512][8192] bf16.
__global__ __launch_bounds__(256) void k_convT(const float* __restrict__ A,
                                               const float* __restrict__ B,
                                               short* __restrict__ XTa,
                                               short* __restrict__ XTb) {
    __shared__ short LT[64][72];
    int bid = blockIdx.x;
    const float* X = (bid >> 10) ? B : A;
    short* XT = (bid >> 10) ? XTb : XTa;
    int rem = bid & 1023;
    int c0 = (rem >> 7) << 6;
    int k0 = (rem & 127) << 6;
    int t = threadIdx.x;

    int cc = t & 15;
    int kb = t >> 4;
    #pragma unroll
    for (int s = 0; s < 4; s++) {
        int kr = kb + s * 16;
        float4 v = *(const float4*)&X[(size_t)(k0 + kr) * DD + c0 + cc * 4];
        LT[cc * 4 + 0][kr] = f2bf_rne(v.x);
        LT[cc * 4 + 1][kr] = f2bf_rne(v.y);
        LT[cc * 4 + 2][kr] = f2bf_rne(v.z);
        LT[cc * 4 + 3][kr] = f2bf_rne(v.w);
    }
    __syncthreads();
    #pragma unroll
    for (int s = 0; s < 2; s++) {
        int idx = s * 256 + t;
        int orow = idx >> 3;
        int och = idx & 7;
        *(uint4*)&XT[(size_t)(c0 + orow) * NN + k0 + och * 8] =
            *(const uint4*)&LT[orow][och * 8];
    }
}

// K3: bf16 MFMA augmented Gram. 448 blocks = 2 mats x 14 tiles x 16 K-chunks.
// LDS: unpadded [128][64] shorts, XOR-swizzled chunks (c' = c ^ (row&7)).
__global__ __launch_bounds__(256, 2) void k_gram(const short* __restrict__ XTa,
                                                 const short* __restrict__ XTb,
                                                 const short* __restrict__ MT,
                                                 float* __restrict__ part) {
    __shared__ short LA[128 * 64];
    __shared__ short LB[128 * 64];

    int bid = blockIdx.x;
    int mat = bid / (NTILE * SPLITK);
    int r = bid % (NTILE * SPLITK);
    int chunk = r / NTILE;
    int tile = r % NTILE;
    const short* XT = mat ? XTb : XTa;
    int ti = c_ti[tile], tj = c_tj[tile];
    const short* PA = XT + (size_t)ti * 128 * NN;
    const short* PB = (tj < 4) ? (XT + (size_t)tj * 128 * NN) : MT;
    int k0 = chunk * (NN / SPLITK);

    int t = threadIdx.x;
    int wave = t >> 6, lane = t & 63;
    int quad = lane >> 4, l16 = lane & 15;
    int x7 = l16 & 7;
    int wrow = (wave >> 1) * 64, wcol = (wave & 1) * 64;

    int srow = lane >> 3;                 // row within 8-row segment
    int sc = (lane & 7) ^ srow;           // swizzled global 16B-chunk index

    f32x4 acc[4][4];
    #pragma unroll
    for (int i = 0; i < 4; i++)
        #pragma unroll
        for (int j = 0; j < 4; j++) acc[i][j] = (f32x4)0.f;

    for (int kk = 0; kk < NN / SPLITK; kk += 64) {
        __syncthreads();
        #pragma unroll
        for (int rr = 0; rr < 4; rr++) {
            int seg = wave * 4 + rr;
            int row = seg * 8 + srow;
            const short* ga = PA + (size_t)row * NN + k0 + kk + sc * 8;
            const short* gb = PB + (size_t)row * NN + k0 + kk + sc * 8;
#ifdef HAVE_GLL
            async16(ga, &LA[seg * 512]);
            async16(gb, &LB[seg * 512]);
#else
            uint4 va = *(const uint4*)ga;
            uint4 vb = *(const uint4*)gb;
            *(uint4*)&LA[seg * 512 + lane * 8] = va;
            *(uint4*)&LB[seg * 512 + lane * 8] = vb;
#endif
        }
        __syncthreads();
        #pragma unroll
        for (int ks = 0; ks < 2; ks++) {
            short8 a[4], b[4];
            #pragma unroll
            for (int mt = 0; mt < 4; mt++)
                a[mt] = *(const short8*)&LA[(wrow + mt * 16 + l16) * 64 +
                                            (((ks * 4 + quad) ^ x7) << 3)];
            #pragma unroll
            for (int nt = 0; nt < 4; nt++)
                b[nt] = *(const short8*)&LB[(wcol + nt * 16 + l16) * 64 +
                                            (((ks * 4 + quad) ^ x7) << 3)];
            #pragma unroll
            for (int mt = 0; mt < 4; mt++)
                #pragma unroll
                for (int nt = 0; nt < 4; nt++)
                    acc[mt][nt] = __builtin_amdgcn_mfma_f32_16x16x32_bf16(
                        a[mt], b[nt], acc[mt][nt], 0, 0, 0);
        }
    }

    float* pbase = part + ((size_t)(mat * NTILE + tile) * SPLITK + chunk) * 16384;
    #pragma unroll
    for (int mt = 0; mt < 4; mt++)
        #pragma unroll
        for (int nt = 0; nt < 4; nt++)
            #pragma unroll
            for (int rj = 0; rj < 4; rj++) {
                int rr2 = wrow + mt * 16 + quad * 4 + rj;
                int cc2 = wcol + nt * 16 + l16;
                pbase[rr2 * 128 + cc2] = acc[mt][nt][rj];
            }
}

// K4: fold SPLITK partials -> Ga/Gb (XX tiles) and RT[class][col] (XM tiles).
__global__ void k_gsum(const float* __restrict__ part,
                       float* __restrict__ Ga, float* __restrict__ Gb,
                       float* __restrict__ RTa, float* __restrict__ RTb) {
    int bid = blockIdx.x;                  // 2*14*64 = 1792
    int mat = bid / (NTILE * 64);
    int rr = bid % (NTILE * 64);
    int tile = rr / 64;
    int e = (rr % 64) * 256 + threadIdx.x;
    const float* p = part + (size_t)(mat * NTILE + tile) * SPLITK * 16384 + e;
    float s = 0.f;
    #pragma unroll
    for (int c = 0; c < SPLITK; c++) s += p[(size_t)c * 16384];
    int rw = e >> 7, cl = e & 127;
    if (tile < NXT) {
        float* G = mat ? Gb : Ga;
        G[(c_ti[tile] * 128 + rw) * DD + c_tj[tile] * 128 + cl] = s;
    } else {
        float* RT = mat ? RTb : RTa;
        RT[cl * DD + (tile - NXT) * 128 + rw] = s;   // [class][col]
    }
}

// K5: column stats (mu from class sums, sumsq from Gram diag) + label histogram.
__global__ void k_stats(const float* __restrict__ Ga, const float* __restrict__ Gb,
                        const float* __restrict__ RTa, const float* __restrict__ RTb,
                        const int* __restrict__ labels,
                        float* mu_a, float* mu_b, float* rs_a, float* rs_b,
                        int* counts) {
    if (blockIdx.x == 2) {
        __shared__ int h[NC];
        int t = threadIdx.x;
        if (t < NC) h[t] = 0;
        __syncthreads();
        for (int i = t; i < NN; i += blockDim.x) atomicAdd(&h[labels[i]], 1);
        __syncthreads();
        if (t < NC) counts[t] = h[t];
        return;
    }
    int mat = blockIdx.x;
    int k = threadIdx.x;
    const float* RT = mat ? RTb : RTa;
    const float* G = mat ? Gb : Ga;
    float s = 0.f;
    for (int c = 0; c < 128; c++) s += RT[c * DD + k];
    float mu = s / (float)NN;
    float sumsq = G[k * DD + k];
    float var = (sumsq - (float)NN * mu * mu) / (float)(NN - 1);
    (mat ? mu_b : mu_a)[k] = mu;
    (mat ? rs_b : rs_a)[k] = rsqrtf(var);
}

// K6: blocks 0..255: term1 over stored tiles (diag w=1, off-diag w=2);
//     blocks 256..355: term2 per class; block 256 also adds term3.
__global__ void k_term(const float* __restrict__ Ga, const float* __restrict__ Gb,
                       const float* __restrict__ RTa, const float* __restrict__ RTb,
                       const float* __restrict__ mu_a, const float* __restrict__ mu_b,
                       const float* __restrict__ rs_a, const float* __restrict__ rs_b,
                       const int* __restrict__ counts, float* out) {
    int bid = blockIdx.x;
    if (bid < 256) {
        float local = 0.f;
        for (int x = bid * 256 + threadIdx.x; x < NXT * 16384; x += 256 * 256) {
            int tile = x >> 14, e = x & 16383;
            int gi = c_ti[tile] * 128 + (e >> 7);
            int gj = c_tj[tile] * 128 + (e & 127);
            float ga = rs_a[gi] * rs_a[gj] * (Ga[gi * DD + gj] - (float)NN * mu_a[gi] * mu_a[gj]);
            float gb = rs_b[gi] * rs_b[gj] * (Gb[gi * DD + gj] - (float)NN * mu_b[gi] * mu_b[gj]);
            local += c_w[tile] * ga * gb;
        }
        float s = block_reduce_sum(local);
        if (threadIdx.x == 0) atomicAdd(out, s * (1.0f / ((float)DD * (float)DD)));
    } else {
        int c = bid - 256;
        float n = (float)counts[c];
        float local = 0.f;
        for (int k = threadIdx.x; k < DD; k += 256) {
            float ta = rs_a[k] * (RTa[c * DD + k] - n * mu_a[k]);
            float tb = rs_b[k] * (RTb[c * DD + k] - n * mu_b[k]);
            local += ta * tb;
        }
        float s = block_reduce_sum(local);
        if (threadIdx.x == 0) {
            float add = s * (-2.0f / (float)DD);
            if (c == 0) {
                float t3 = 0.f;
                for (int cc = 0; cc < NC; cc++) {
                    float nc = (float)counts[cc];
                    t3 += nc * nc;
                }
                add += t3;
            }
            atomicAdd(out, add);
        }
    }
}

extern "C" void kernel_launch(void* const* d_in, const int* in_sizes, int n_in,
                              void* d_out, int out_size, void* d_ws, size_t ws_size,
                              hipStream_t stream) {
    const float* z_a = (const float*)d_in[0];
    const float* z_b = (const float*)d_in[1];
    const int* labels = (const int*)d_in[2];
    float* out = (float*)d_out;
    char* wsb = (char*)d_ws;

    float* Ga = (float*)(wsb + GA_B);
    float* Gb = (float*)(wsb + GB_B);
    float* RTa = (float*)(wsb + RTA_B);
    float* RTb = (float*)(wsb + RTB_B);
    float* mu_a = (float*)(wsb + MUA_B);
    float* mu_b = (float*)(wsb + MUB_B);
    float* rs_a = (float*)(wsb + RSA_B);
    float* rs_b = (float*)(wsb + RSB_B);
    int* counts = (int*)(wsb + CNT_B);
    short* XTa = (short*)(wsb + XTA_B);
    short* XTb = (short*)(wsb + XTB_B);
    short* MT = (short*)(wsb + MT_B);
    float* part = (float*)(wsb + PART_B);

    hipLaunchKernelGGL(k_init, dim3(129), dim3(256), 0, stream, labels, MT, out);
    hipLaunchKernelGGL(k_convT, dim3(2048), dim3(256), 0, stream, z_a, z_b, XTa, XTb);
    hipLaunchKernelGGL(k_gram, dim3(2 * NTILE * SPLITK), dim3(256), 0, stream,
                       XTa, XTb, MT, part);
    hipLaunchKernelGGL(k_gsum, dim3(2 * NTILE * 64), dim3(256), 0, stream,
                       part, Ga, Gb, RTa, RTb);
    hipLaunchKernelGGL(k_stats, dim3(3), dim3(512), 0, stream,
                       Ga, Gb, RTa, RTb, labels, mu_a, mu_b, rs_a, rs_b, counts);
    hipLaunchKernelGGL(k_term, dim3(356), dim3(256), 0, stream,
                       Ga, Gb, RTa, RTb, mu_a, mu_b, rs_a, rs_b, counts, out);
}